// Round 1
// baseline (2285.255 us; speedup 1.0000x reference)
//
#include <hip/hip_runtime.h>
#include <hip/hip_bf16.h>

// GCN1: 3-layer GraphConv x 4 graphs -> scalar grand mean.
// Plan: per-graph CSR build (hist + scan + scatter), deg norms folded into
// bf16 stores; SpMM = per-node (one wave) gather-accumulate from CSR;
// GEMM = MFMA 16x16x32 bf16 with W transposed/padded to bf16 once;
// layer-3 GEMM reduces relu(y) directly into a double accumulator.

#define NN 50000
#define EN 800000

typedef unsigned int uint;
typedef unsigned short ushort;
typedef short s8v __attribute__((ext_vector_type(8)));
typedef float f4v __attribute__((ext_vector_type(4)));

__device__ inline ushort f2bf(float f) {
    uint u = __float_as_uint(f);
    uint r = (u + 0x7FFFu + ((u >> 16) & 1u)) >> 16;
    return (ushort)r;
}
__device__ inline uint pk2(float lo, float hi) {
    return (uint)f2bf(lo) | ((uint)f2bf(hi) << 16);
}
__device__ inline f4v mfma16(s8v a, s8v b, f4v c) {
    return __builtin_amdgcn_mfma_f32_16x16x32_bf16(a, b, c, 0, 0, 0);
}

struct GP { const int* p[4]; };

// ---- CSR build -------------------------------------------------------------

__global__ __launch_bounds__(256) void hist_kernel(GP src, GP dst, int* degs, int* degd) {
    int idx = blockIdx.x * 256 + threadIdx.x;
    if (idx >= 4 * EN) return;
    int g = idx / EN, e = idx - g * EN;
    atomicAdd(&degs[g * NN + src.p[g][e]], 1);
    atomicAdd(&degd[g * NN + dst.p[g][e]], 1);
}

__global__ __launch_bounds__(1024) void scan_kernel(const int* __restrict__ degd_all,
                                                    int* __restrict__ rs_all,
                                                    int* __restrict__ cur_all) {
    int g = blockIdx.x;
    const int* deg = degd_all + g * NN;
    int* rs = rs_all + g * (NN + 1);
    int* cur = cur_all + g * NN;
    __shared__ int wsum[16];
    __shared__ int carry;
    int tid = threadIdx.x, lane = tid & 63, w = tid >> 6;
    if (tid == 0) carry = 0;
    for (int base = 0; base < NN; base += 1024) {
        int i = base + tid;
        int v = (i < NN) ? deg[i] : 0;
        int x = v;
        #pragma unroll
        for (int off = 1; off < 64; off <<= 1) {
            int t = __shfl_up(x, off, 64);
            if (lane >= off) x += t;
        }
        __syncthreads();               // prior iter done with wsum
        if (lane == 63) wsum[w] = x;   // wave totals
        __syncthreads();
        if (tid == 0) {
            int run = carry;
            #pragma unroll
            for (int j = 0; j < 16; j++) { int t = wsum[j]; wsum[j] = run; run += t; }
            carry = run;
        }
        __syncthreads();
        int excl = wsum[w] + x - v;
        if (i < NN) { rs[i] = excl; cur[i] = excl; }
    }
    __syncthreads();
    if (tid == 0) rs[NN] = carry;
}

__global__ __launch_bounds__(256) void scatter_kernel(GP src, GP dst, int* cur, int* csr) {
    int idx = blockIdx.x * 256 + threadIdx.x;
    if (idx >= 4 * EN) return;
    int g = idx / EN, e = idx - g * EN;
    int d = dst.p[g][e];
    int pos = atomicAdd(&cur[g * NN + d], 1);
    csr[(size_t)g * EN + pos] = src.p[g][e];
}

__global__ __launch_bounds__(256) void norms_kernel(const int* __restrict__ degs,
                                                    const int* __restrict__ degd,
                                                    float* __restrict__ ns,
                                                    float* __restrict__ nd) {
    int i = blockIdx.x * 256 + threadIdx.x;
    if (i >= 4 * NN) return;
    ns[i] = rsqrtf((float)max(degs[i], 1));
    nd[i] = rsqrtf((float)max(degd[i], 1));
}

// ---- weight transpose/pad to bf16: Wt[n][k], stride WS = K+8 ---------------

__global__ __launch_bounds__(256) void wtrans_kernel(const float* __restrict__ W,
                                                     ushort* __restrict__ Wt,
                                                     int Kreal, int WS) {
    int idx = blockIdx.x * 256 + threadIdx.x;
    if (idx >= 320 * WS) return;
    int n = idx / WS, k = idx - n * WS;
    float v = (n < 304 && k < Kreal) ? W[k * 304 + n] : 0.f;
    Wt[idx] = f2bf(v);
}

// ---- prescale: xs = bf16(x * ns), N x 128 ----------------------------------

__global__ __launch_bounds__(256) void prescale_kernel(const float* __restrict__ x,
                                                       const float* __restrict__ ns,
                                                       uint* __restrict__ xs) {
    int idx = blockIdx.x * 256 + threadIdx.x;   // over NN*32 float4s
    if (idx >= NN * 32) return;
    int row = idx >> 5;
    float nv = ns[row];
    float4 v = ((const float4*)x)[idx];
    ((uint2*)xs)[idx] = make_uint2(pk2(v.x * nv, v.y * nv), pk2(v.z * nv, v.w * nv));
}

// ---- SpMM: one wave per node, CSR gather-accumulate ------------------------

__global__ __launch_bounds__(256) void spmm128_kernel(const uint* __restrict__ xs,
                                                      const int* __restrict__ rs,
                                                      const int* __restrict__ csr,
                                                      const float* __restrict__ nd,
                                                      uint* __restrict__ out) {
    int wv = threadIdx.x >> 6, lane = threadIdx.x & 63;
    int node = blockIdx.x * 4 + wv;
    int e0 = rs[node], e1 = rs[node + 1];
    float a0 = 0.f, a1 = 0.f;
    for (int e = e0; e < e1; e++) {
        int s = __builtin_amdgcn_readfirstlane(csr[e]);
        uint d = xs[(size_t)s * 64 + lane];
        a0 += __uint_as_float(d << 16);
        a1 += __uint_as_float(d & 0xFFFF0000u);
    }
    float nv = nd[node];
    out[(size_t)node * 64 + lane] = pk2(a0 * nv, a1 * nv);
}

__global__ __launch_bounds__(256) void spmm320_kernel(const uint* __restrict__ h,
                                                      const int* __restrict__ rs,
                                                      const int* __restrict__ csr,
                                                      const float* __restrict__ nd,
                                                      uint* __restrict__ out) {
    int wv = threadIdx.x >> 6, lane = threadIdx.x & 63;
    int node = blockIdx.x * 4 + wv;
    int e0 = rs[node], e1 = rs[node + 1];
    float a0 = 0.f, a1 = 0.f, b0 = 0.f, b1 = 0.f, c0 = 0.f, c1 = 0.f;
    bool third = lane < 32;
    for (int e = e0; e < e1; e++) {
        int s = __builtin_amdgcn_readfirstlane(csr[e]);
        const uint* row = h + (size_t)s * 160;
        uint d0 = row[lane];
        uint d1 = row[64 + lane];
        a0 += __uint_as_float(d0 << 16); a1 += __uint_as_float(d0 & 0xFFFF0000u);
        b0 += __uint_as_float(d1 << 16); b1 += __uint_as_float(d1 & 0xFFFF0000u);
        if (third) {
            uint d2 = row[128 + lane];
            c0 += __uint_as_float(d2 << 16); c1 += __uint_as_float(d2 & 0xFFFF0000u);
        }
    }
    float nv = nd[node];
    uint* orow = out + (size_t)node * 160;
    orow[lane] = pk2(a0 * nv, a1 * nv);
    orow[64 + lane] = pk2(b0 * nv, b1 * nv);
    if (third) orow[128 + lane] = pk2(c0 * nv, c1 * nv);
}

// ---- GEMM: C[M x 320] = A[M x K] @ Wt^T, epilogue relu(+bias) --------------
// Block: 256 thr (4 waves), BM=128 (wave: 2 row-tiles), BN=80 (5 n-tiles),
// grid (ceil(M/128), 4). Wt staged in LDS from pre-transposed bf16 global.

template<int KSTEPS, bool REDUCE>
__global__ __launch_bounds__(256) void gemm_kernel(const ushort* __restrict__ A, int astride,
                                                   const ushort* __restrict__ Wt,
                                                   const float* __restrict__ bias,
                                                   const float* __restrict__ ns,
                                                   ushort* __restrict__ Hout,
                                                   double* __restrict__ accum,
                                                   int M) {
    constexpr int K = KSTEPS * 32;
    constexpr int WS = K + 8;   // pad: stride % 32 dwords == 4 -> 2-way LDS conflicts (free)
    __shared__ __align__(16) ushort wt[80 * WS];
    __shared__ float redbuf[4];
    int tid = threadIdx.x, lane = tid & 63, wv = tid >> 6;
    int nb = blockIdx.y * 80;
    int r0 = blockIdx.x * 128 + wv * 32;

    {   // stage 80 rows of Wt (16B vectors)
        const s8v* src = (const s8v*)(Wt + (size_t)nb * WS);
        s8v* dst = (s8v*)wt;
        for (int i = tid; i < 80 * WS / 8; i += 256) dst[i] = src[i];
    }
    __syncthreads();

    f4v acc[2][5];
    #pragma unroll
    for (int t = 0; t < 2; t++)
        #pragma unroll
        for (int j = 0; j < 5; j++) acc[t][j] = (f4v){0.f, 0.f, 0.f, 0.f};

    int m15 = lane & 15;
    int kq = (lane >> 4) * 8;
    int ar0 = min(r0 + m15, M - 1);
    int ar1 = min(r0 + 16 + m15, M - 1);
    const ushort* a0p = A + (size_t)ar0 * astride + kq;
    const ushort* a1p = A + (size_t)ar1 * astride + kq;
    const ushort* bb = wt + (size_t)m15 * WS + kq;

    #pragma unroll
    for (int ks = 0; ks < KSTEPS; ks++) {
        s8v af0 = *(const s8v*)(a0p + ks * 32);
        s8v af1 = *(const s8v*)(a1p + ks * 32);
        #pragma unroll
        for (int nt = 0; nt < 5; nt++) {
            s8v bf = *(const s8v*)(bb + nt * 16 * WS + ks * 32);
            acc[0][nt] = mfma16(af0, bf, acc[0][nt]);
            acc[1][nt] = mfma16(af1, bf, acc[1][nt]);
        }
    }

    int rq = (lane >> 4) * 4;   // C/D: col = lane&15, row = (lane>>4)*4 + reg
    if constexpr (!REDUCE) {
        float nsv[2][4];
        #pragma unroll
        for (int t = 0; t < 2; t++)
            #pragma unroll
            for (int r = 0; r < 4; r++) {
                int row = r0 + t * 16 + rq + r;
                nsv[t][r] = (row < M) ? ns[row] : 0.f;
            }
        #pragma unroll
        for (int nt = 0; nt < 5; nt++) {
            int col = nb + nt * 16 + m15;
            float bv = (col < 304) ? bias[col] : 0.f;
            #pragma unroll
            for (int t = 0; t < 2; t++)
                #pragma unroll
                for (int r = 0; r < 4; r++) {
                    int row = r0 + t * 16 + rq + r;
                    if (row < M) {
                        float y = fmaxf(acc[t][nt][r] + bv, 0.f) * nsv[t][r];
                        Hout[(size_t)row * 320 + col] = f2bf(y);
                    }
                }
        }
    } else {
        float s = 0.f;
        #pragma unroll
        for (int nt = 0; nt < 5; nt++) {
            int col = nb + nt * 16 + m15;
            float bv = (col < 304) ? bias[col] : 0.f;
            #pragma unroll
            for (int t = 0; t < 2; t++)
                #pragma unroll
                for (int r = 0; r < 4; r++) {
                    int row = r0 + t * 16 + rq + r;
                    if (row < M) s += fmaxf(acc[t][nt][r] + bv, 0.f);
                }
        }
        #pragma unroll
        for (int off = 32; off; off >>= 1) s += __shfl_xor(s, off, 64);
        if (lane == 0) redbuf[wv] = s;
        __syncthreads();
        if (tid == 0) {
            double b = (double)redbuf[0] + redbuf[1] + redbuf[2] + redbuf[3];
            atomicAdd(accum, b);
        }
    }
}

__global__ void finalize_kernel(const double* __restrict__ accum, float* __restrict__ out) {
    out[0] = (float)(accum[0] / (double)(4.0 * NN * 304.0));
}

// ---- host ------------------------------------------------------------------

extern "C" void kernel_launch(void* const* d_in, const int* in_sizes, int n_in,
                              void* d_out, int out_size, void* d_ws, size_t ws_size,
                              hipStream_t stream) {
    char* w = (char*)d_ws;
    auto alloc = [&](size_t bytes) {
        char* p = w;
        w += (bytes + 255) & ~(size_t)255;
        return p;
    };
    double* accum  = (double*)alloc(256);
    int*    degs   = (int*)alloc((size_t)4 * NN * 4);   // 800000B, 256-aligned run
    int*    degd   = (int*)alloc((size_t)4 * NN * 4);   // contiguous with degs
    int*    rs     = (int*)alloc((size_t)4 * (NN + 1) * 4);
    int*    cur    = (int*)alloc((size_t)4 * NN * 4);
    float*  nsrc   = (float*)alloc((size_t)4 * NN * 4);
    float*  ndst   = (float*)alloc((size_t)4 * NN * 4);
    int*    csr    = (int*)alloc((size_t)4 * EN * 4);
    ushort* wt1    = (ushort*)alloc((size_t)320 * 136 * 2);
    ushort* wt2    = (ushort*)alloc((size_t)320 * 328 * 2);
    ushort* wt3    = (ushort*)alloc((size_t)320 * 328 * 2);
    uint*   xs     = (uint*)alloc((size_t)NN * 64 * 4);
    uint*   m1     = (uint*)alloc((size_t)NN * 64 * 4);
    uint*   hbuf   = (uint*)alloc((size_t)NN * 160 * 4);
    uint*   mbuf   = (uint*)alloc((size_t)NN * 160 * 4);

    hipMemsetAsync(accum, 0, 256, stream);
    hipMemsetAsync(degs, 0, (size_t)8 * NN * 4, stream);   // degs + degd

    wtrans_kernel<<<(320 * 136 + 255) / 256, 256, 0, stream>>>((const float*)d_in[12], wt1, 128, 136);
    wtrans_kernel<<<(320 * 328 + 255) / 256, 256, 0, stream>>>((const float*)d_in[14], wt2, 304, 328);
    wtrans_kernel<<<(320 * 328 + 255) / 256, 256, 0, stream>>>((const float*)d_in[16], wt3, 304, 328);

    GP S, D;
    for (int g = 0; g < 4; g++) {
        S.p[g] = (const int*)d_in[1 + 3 * g];
        D.p[g] = (const int*)d_in[2 + 3 * g];
    }
    hist_kernel<<<(4 * EN + 255) / 256, 256, 0, stream>>>(S, D, degs, degd);
    scan_kernel<<<4, 1024, 0, stream>>>(degd, rs, cur);
    scatter_kernel<<<(4 * EN + 255) / 256, 256, 0, stream>>>(S, D, cur, csr);
    norms_kernel<<<(4 * NN + 255) / 256, 256, 0, stream>>>(degs, degd, nsrc, ndst);

    const float* b1 = (const float*)d_in[13];
    const float* b2 = (const float*)d_in[15];
    const float* b3 = (const float*)d_in[17];
    dim3 ggrid((NN + 127) / 128, 4);

    for (int g = 0; g < 4; g++) {
        const float* xin = (const float*)d_in[3 * g];
        const float* nsg = nsrc + g * NN;
        const float* ndg = ndst + g * NN;
        const int* rsg = rs + g * (NN + 1);
        const int* csrg = csr + (size_t)g * EN;

        prescale_kernel<<<(NN * 32 + 255) / 256, 256, 0, stream>>>(xin, nsg, xs);
        spmm128_kernel<<<NN / 4, 256, 0, stream>>>(xs, rsg, csrg, ndg, m1);
        gemm_kernel<4, false><<<ggrid, 256, 0, stream>>>((const ushort*)m1, 128, wt1, b1, nsg,
                                                         (ushort*)hbuf, nullptr, NN);
        spmm320_kernel<<<NN / 4, 256, 0, stream>>>(hbuf, rsg, csrg, ndg, mbuf);
        gemm_kernel<10, false><<<ggrid, 256, 0, stream>>>((const ushort*)mbuf, 320, wt2, b2, nsg,
                                                          (ushort*)hbuf, nullptr, NN);
        spmm320_kernel<<<NN / 4, 256, 0, stream>>>(hbuf, rsg, csrg, ndg, mbuf);
        gemm_kernel<10, true><<<ggrid, 256, 0, stream>>>((const ushort*)mbuf, 320, wt3, b3, nullptr,
                                                         nullptr, accum, NN);
    }
    finalize_kernel<<<1, 1, 0, stream>>>(accum, (float*)d_out);
}

// Round 2
// 2156.270 us; speedup vs baseline: 1.0598x; 1.0598x over previous
//
#include <hip/hip_runtime.h>
#include <hip/hip_bf16.h>

// GCN1: 3-layer GraphConv x 4 graphs -> scalar grand mean.
// R2: fp8(e4m3) intermediates for the gather buffers (xs, h) -> halves SpMM
// gather traffic. SpMM accumulates fp32, emits bf16 m-buffer for MFMA GEMM.
// GEMM epilogue writes fp8 h. Layer-3 GEMM reduces relu(y) into double accum.

#define NN 50000
#define EN 800000

typedef unsigned int uint;
typedef unsigned short ushort;
typedef unsigned char uchar;
typedef short s8v __attribute__((ext_vector_type(8)));
typedef float f4v __attribute__((ext_vector_type(4)));
typedef float f2v __attribute__((ext_vector_type(2)));

__device__ inline ushort f2bf(float f) {
    uint u = __float_as_uint(f);
    uint r = (u + 0x7FFFu + ((u >> 16) & 1u)) >> 16;
    return (ushort)r;
}
__device__ inline uint pk2(float lo, float hi) {
    return (uint)f2bf(lo) | ((uint)f2bf(hi) << 16);
}
__device__ inline f4v mfma16(s8v a, s8v b, f4v c) {
    return __builtin_amdgcn_mfma_f32_16x16x32_bf16(a, b, c, 0, 0, 0);
}
__device__ inline uchar f2fp8(float f) {
    return (uchar)(__builtin_amdgcn_cvt_pk_fp8_f32(f, 0.f, 0, false) & 0xFF);
}

struct GP { const int* p[4]; };

// ---- CSR build -------------------------------------------------------------

__global__ __launch_bounds__(256) void hist_kernel(GP src, GP dst, int* degs, int* degd) {
    int idx = blockIdx.x * 256 + threadIdx.x;
    if (idx >= 4 * EN) return;
    int g = idx / EN, e = idx - g * EN;
    atomicAdd(&degs[g * NN + src.p[g][e]], 1);
    atomicAdd(&degd[g * NN + dst.p[g][e]], 1);
}

__global__ __launch_bounds__(1024) void scan_kernel(const int* __restrict__ degd_all,
                                                    int* __restrict__ rs_all,
                                                    int* __restrict__ cur_all) {
    int g = blockIdx.x;
    const int* deg = degd_all + g * NN;
    int* rs = rs_all + g * (NN + 1);
    int* cur = cur_all + g * NN;
    __shared__ int wsum[16];
    __shared__ int carry;
    int tid = threadIdx.x, lane = tid & 63, w = tid >> 6;
    if (tid == 0) carry = 0;
    for (int base = 0; base < NN; base += 1024) {
        int i = base + tid;
        int v = (i < NN) ? deg[i] : 0;
        int x = v;
        #pragma unroll
        for (int off = 1; off < 64; off <<= 1) {
            int t = __shfl_up(x, off, 64);
            if (lane >= off) x += t;
        }
        __syncthreads();               // prior iter done with wsum
        if (lane == 63) wsum[w] = x;   // wave totals
        __syncthreads();
        if (tid == 0) {
            int run = carry;
            #pragma unroll
            for (int j = 0; j < 16; j++) { int t = wsum[j]; wsum[j] = run; run += t; }
            carry = run;
        }
        __syncthreads();
        int excl = wsum[w] + x - v;
        if (i < NN) { rs[i] = excl; cur[i] = excl; }
    }
    __syncthreads();
    if (tid == 0) rs[NN] = carry;
}

__global__ __launch_bounds__(256) void scatter_kernel(GP src, GP dst, int* cur, int* csr) {
    int idx = blockIdx.x * 256 + threadIdx.x;
    if (idx >= 4 * EN) return;
    int g = idx / EN, e = idx - g * EN;
    int d = dst.p[g][e];
    int pos = atomicAdd(&cur[g * NN + d], 1);
    csr[(size_t)g * EN + pos] = src.p[g][e];
}

__global__ __launch_bounds__(256) void norms_kernel(const int* __restrict__ degs,
                                                    const int* __restrict__ degd,
                                                    float* __restrict__ ns,
                                                    float* __restrict__ nd) {
    int i = blockIdx.x * 256 + threadIdx.x;
    if (i >= 4 * NN) return;
    ns[i] = rsqrtf((float)max(degs[i], 1));
    nd[i] = rsqrtf((float)max(degd[i], 1));
}

// ---- weight transpose/pad to bf16: Wt[n][k], stride WS = K+8 ---------------

__global__ __launch_bounds__(256) void wtrans_kernel(const float* __restrict__ W,
                                                     ushort* __restrict__ Wt,
                                                     int Kreal, int WS) {
    int idx = blockIdx.x * 256 + threadIdx.x;
    if (idx >= 320 * WS) return;
    int n = idx / WS, k = idx - n * WS;
    float v = (n < 304 && k < Kreal) ? W[k * 304 + n] : 0.f;
    Wt[idx] = f2bf(v);
}

// ---- prescale: xs = fp8(x * ns), N x 128 (32 dwords/row) -------------------

__global__ __launch_bounds__(256) void prescale_kernel(const float* __restrict__ x,
                                                       const float* __restrict__ ns,
                                                       uint* __restrict__ xs) {
    int idx = blockIdx.x * 256 + threadIdx.x;   // over NN*32 float4s
    if (idx >= NN * 32) return;
    int row = idx >> 5;
    float nv = ns[row];
    float4 v = ((const float4*)x)[idx];
    int p = 0;
    p = __builtin_amdgcn_cvt_pk_fp8_f32(v.x * nv, v.y * nv, p, false);
    p = __builtin_amdgcn_cvt_pk_fp8_f32(v.z * nv, v.w * nv, p, true);
    xs[idx] = (uint)p;
}

// ---- SpMM: one wave per node, CSR gather-accumulate (fp8 in, bf16 out) -----

// xs rows: 32 dwords (128 fp8). out rows: 64 dwords (128 bf16).
// 2 edges/iter: lanes 0-31 edge e, lanes 32-63 edge e+1.
__global__ __launch_bounds__(256) void spmm128_kernel(const uint* __restrict__ xs,
                                                      const int* __restrict__ rs,
                                                      const int* __restrict__ csr,
                                                      const float* __restrict__ nd,
                                                      uint* __restrict__ out) {
    int wv = threadIdx.x >> 6, lane = threadIdx.x & 63;
    int node = blockIdx.x * 4 + wv;
    int e0 = rs[node], e1 = rs[node + 1];
    int half = lane >> 5, l32 = lane & 31;
    float a0 = 0.f, a1 = 0.f, a2 = 0.f, a3 = 0.f;
    for (int e = e0; e < e1; e += 2) {
        int idx = e + half;
        if (idx < e1) {
            int s = csr[idx];
            uint d = xs[(size_t)s * 32 + l32];
            f2v lo = __builtin_amdgcn_cvt_pk_f32_fp8(d, false);
            f2v hi = __builtin_amdgcn_cvt_pk_f32_fp8(d, true);
            a0 += lo[0]; a1 += lo[1]; a2 += hi[0]; a3 += hi[1];
        }
    }
    a0 += __shfl_xor(a0, 32, 64);
    a1 += __shfl_xor(a1, 32, 64);
    a2 += __shfl_xor(a2, 32, 64);
    a3 += __shfl_xor(a3, 32, 64);
    if (half == 0) {
        float nv = nd[node];
        uint2 o = make_uint2(pk2(a0 * nv, a1 * nv), pk2(a2 * nv, a3 * nv));
        ((uint2*)(out + (size_t)node * 64))[l32] = o;
    }
}

// h rows: 80 dwords (320 fp8). out rows: 160 dwords (320 bf16).
__global__ __launch_bounds__(256) void spmm320_kernel(const uint* __restrict__ h,
                                                      const int* __restrict__ rs,
                                                      const int* __restrict__ csr,
                                                      const float* __restrict__ nd,
                                                      uint* __restrict__ out) {
    int wv = threadIdx.x >> 6, lane = threadIdx.x & 63;
    int node = blockIdx.x * 4 + wv;
    int e0 = rs[node], e1 = rs[node + 1];
    float a0 = 0.f, a1 = 0.f, a2 = 0.f, a3 = 0.f;
    float b0 = 0.f, b1 = 0.f, b2 = 0.f, b3 = 0.f;
    bool tail = lane < 16;
    for (int e = e0; e < e1; e++) {
        int s = __builtin_amdgcn_readfirstlane(csr[e]);
        const uint* row = h + (size_t)s * 80;
        uint d0 = row[lane];
        f2v lo = __builtin_amdgcn_cvt_pk_f32_fp8(d0, false);
        f2v hi = __builtin_amdgcn_cvt_pk_f32_fp8(d0, true);
        a0 += lo[0]; a1 += lo[1]; a2 += hi[0]; a3 += hi[1];
        if (tail) {
            uint d1 = row[64 + lane];
            f2v lo1 = __builtin_amdgcn_cvt_pk_f32_fp8(d1, false);
            f2v hi1 = __builtin_amdgcn_cvt_pk_f32_fp8(d1, true);
            b0 += lo1[0]; b1 += lo1[1]; b2 += hi1[0]; b3 += hi1[1];
        }
    }
    float nv = nd[node];
    uint* orow = out + (size_t)node * 160;
    ((uint2*)orow)[lane] = make_uint2(pk2(a0 * nv, a1 * nv), pk2(a2 * nv, a3 * nv));
    if (tail)
        ((uint2*)orow)[64 + lane] = make_uint2(pk2(b0 * nv, b1 * nv), pk2(b2 * nv, b3 * nv));
}

// ---- GEMM: C[M x 320] = A[M x K] @ Wt^T, epilogue relu(+bias) --------------
// Block: 256 thr (4 waves), BM=128 (wave: 2 row-tiles), BN=80 (5 n-tiles),
// grid (ceil(M/128), 4). Wt staged in LDS from pre-transposed bf16 global.
// !REDUCE: writes fp8 h rows (stride 320 bytes). REDUCE: sum into double.

template<int KSTEPS, bool REDUCE>
__global__ __launch_bounds__(256) void gemm_kernel(const ushort* __restrict__ A, int astride,
                                                   const ushort* __restrict__ Wt,
                                                   const float* __restrict__ bias,
                                                   const float* __restrict__ ns,
                                                   uchar* __restrict__ Hout,
                                                   double* __restrict__ accum,
                                                   int M) {
    constexpr int K = KSTEPS * 32;
    constexpr int WS = K + 8;   // pad: stride % 32 dwords == 4 -> 2-way LDS conflicts (free)
    __shared__ __align__(16) ushort wt[80 * WS];
    __shared__ float redbuf[4];
    int tid = threadIdx.x, lane = tid & 63, wv = tid >> 6;
    int nb = blockIdx.y * 80;
    int r0 = blockIdx.x * 128 + wv * 32;

    {   // stage 80 rows of Wt (16B vectors)
        const s8v* src = (const s8v*)(Wt + (size_t)nb * WS);
        s8v* dst = (s8v*)wt;
        for (int i = tid; i < 80 * WS / 8; i += 256) dst[i] = src[i];
    }
    __syncthreads();

    f4v acc[2][5];
    #pragma unroll
    for (int t = 0; t < 2; t++)
        #pragma unroll
        for (int j = 0; j < 5; j++) acc[t][j] = (f4v){0.f, 0.f, 0.f, 0.f};

    int m15 = lane & 15;
    int kq = (lane >> 4) * 8;
    int ar0 = min(r0 + m15, M - 1);
    int ar1 = min(r0 + 16 + m15, M - 1);
    const ushort* a0p = A + (size_t)ar0 * astride + kq;
    const ushort* a1p = A + (size_t)ar1 * astride + kq;
    const ushort* bb = wt + (size_t)m15 * WS + kq;

    #pragma unroll
    for (int ks = 0; ks < KSTEPS; ks++) {
        s8v af0 = *(const s8v*)(a0p + ks * 32);
        s8v af1 = *(const s8v*)(a1p + ks * 32);
        #pragma unroll
        for (int nt = 0; nt < 5; nt++) {
            s8v bf = *(const s8v*)(bb + nt * 16 * WS + ks * 32);
            acc[0][nt] = mfma16(af0, bf, acc[0][nt]);
            acc[1][nt] = mfma16(af1, bf, acc[1][nt]);
        }
    }

    int rq = (lane >> 4) * 4;   // C/D: col = lane&15, row = (lane>>4)*4 + reg
    if constexpr (!REDUCE) {
        float nsv[2][4];
        #pragma unroll
        for (int t = 0; t < 2; t++)
            #pragma unroll
            for (int r = 0; r < 4; r++) {
                int row = r0 + t * 16 + rq + r;
                nsv[t][r] = (row < M) ? ns[row] : 0.f;
            }
        #pragma unroll
        for (int nt = 0; nt < 5; nt++) {
            int col = nb + nt * 16 + m15;
            float bv = (col < 304) ? bias[col] : 0.f;
            #pragma unroll
            for (int t = 0; t < 2; t++)
                #pragma unroll
                for (int r = 0; r < 4; r++) {
                    int row = r0 + t * 16 + rq + r;
                    if (row < M) {
                        float y = fmaxf(acc[t][nt][r] + bv, 0.f) * nsv[t][r];
                        Hout[(size_t)row * 320 + col] = f2fp8(y);
                    }
                }
        }
    } else {
        float s = 0.f;
        #pragma unroll
        for (int nt = 0; nt < 5; nt++) {
            int col = nb + nt * 16 + m15;
            float bv = (col < 304) ? bias[col] : 0.f;
            #pragma unroll
            for (int t = 0; t < 2; t++)
                #pragma unroll
                for (int r = 0; r < 4; r++) {
                    int row = r0 + t * 16 + rq + r;
                    if (row < M && col < 304) s += fmaxf(acc[t][nt][r] + bv, 0.f);
                }
        }
        #pragma unroll
        for (int off = 32; off; off >>= 1) s += __shfl_xor(s, off, 64);
        if (lane == 0) redbuf[wv] = s;
        __syncthreads();
        if (tid == 0) {
            double b = (double)redbuf[0] + redbuf[1] + redbuf[2] + redbuf[3];
            atomicAdd(accum, b);
        }
    }
}

__global__ void finalize_kernel(const double* __restrict__ accum, float* __restrict__ out) {
    out[0] = (float)(accum[0] / (double)(4.0 * NN * 304.0));
}

// ---- host ------------------------------------------------------------------

extern "C" void kernel_launch(void* const* d_in, const int* in_sizes, int n_in,
                              void* d_out, int out_size, void* d_ws, size_t ws_size,
                              hipStream_t stream) {
    char* w = (char*)d_ws;
    auto alloc = [&](size_t bytes) {
        char* p = w;
        w += (bytes + 255) & ~(size_t)255;
        return p;
    };
    double* accum  = (double*)alloc(256);
    int*    degs   = (int*)alloc((size_t)4 * NN * 4);   // contiguous with degd
    int*    degd   = (int*)alloc((size_t)4 * NN * 4);
    int*    rs     = (int*)alloc((size_t)4 * (NN + 1) * 4);
    int*    cur    = (int*)alloc((size_t)4 * NN * 4);
    float*  nsrc   = (float*)alloc((size_t)4 * NN * 4);
    float*  ndst   = (float*)alloc((size_t)4 * NN * 4);
    int*    csr    = (int*)alloc((size_t)4 * EN * 4);
    ushort* wt1    = (ushort*)alloc((size_t)320 * 136 * 2);
    ushort* wt2    = (ushort*)alloc((size_t)320 * 328 * 2);
    ushort* wt3    = (ushort*)alloc((size_t)320 * 328 * 2);
    uint*   xs     = (uint*)alloc((size_t)NN * 32 * 4);    // fp8 N x 128
    uint*   m1     = (uint*)alloc((size_t)NN * 64 * 4);    // bf16 N x 128
    uint*   hbuf   = (uint*)alloc((size_t)NN * 80 * 4);    // fp8 N x 320
    uint*   mbuf   = (uint*)alloc((size_t)NN * 160 * 4);   // bf16 N x 320

    hipMemsetAsync(accum, 0, 256, stream);
    hipMemsetAsync(degs, 0, (size_t)8 * NN * 4, stream);   // degs + degd

    wtrans_kernel<<<(320 * 136 + 255) / 256, 256, 0, stream>>>((const float*)d_in[12], wt1, 128, 136);
    wtrans_kernel<<<(320 * 328 + 255) / 256, 256, 0, stream>>>((const float*)d_in[14], wt2, 304, 328);
    wtrans_kernel<<<(320 * 328 + 255) / 256, 256, 0, stream>>>((const float*)d_in[16], wt3, 304, 328);

    GP S, D;
    for (int g = 0; g < 4; g++) {
        S.p[g] = (const int*)d_in[1 + 3 * g];
        D.p[g] = (const int*)d_in[2 + 3 * g];
    }
    hist_kernel<<<(4 * EN + 255) / 256, 256, 0, stream>>>(S, D, degs, degd);
    scan_kernel<<<4, 1024, 0, stream>>>(degd, rs, cur);
    scatter_kernel<<<(4 * EN + 255) / 256, 256, 0, stream>>>(S, D, cur, csr);
    norms_kernel<<<(4 * NN + 255) / 256, 256, 0, stream>>>(degs, degd, nsrc, ndst);

    const float* b1 = (const float*)d_in[13];
    const float* b2 = (const float*)d_in[15];
    const float* b3 = (const float*)d_in[17];
    dim3 ggrid((NN + 127) / 128, 4);

    for (int g = 0; g < 4; g++) {
        const float* xin = (const float*)d_in[3 * g];
        const float* nsg = nsrc + g * NN;
        const float* ndg = ndst + g * NN;
        const int* rsg = rs + g * (NN + 1);
        const int* csrg = csr + (size_t)g * EN;

        prescale_kernel<<<(NN * 32 + 255) / 256, 256, 0, stream>>>(xin, nsg, xs);
        spmm128_kernel<<<NN / 4, 256, 0, stream>>>(xs, rsg, csrg, ndg, m1);
        gemm_kernel<4, false><<<ggrid, 256, 0, stream>>>((const ushort*)m1, 128, wt1, b1, nsg,
                                                         (uchar*)hbuf, nullptr, NN);
        spmm320_kernel<<<NN / 4, 256, 0, stream>>>(hbuf, rsg, csrg, ndg, mbuf);
        gemm_kernel<10, false><<<ggrid, 256, 0, stream>>>((const ushort*)mbuf, 320, wt2, b2, nsg,
                                                          (uchar*)hbuf, nullptr, NN);
        spmm320_kernel<<<NN / 4, 256, 0, stream>>>(hbuf, rsg, csrg, ndg, mbuf);
        gemm_kernel<10, true><<<ggrid, 256, 0, stream>>>((const ushort*)mbuf, 320, wt3, b3, nullptr,
                                                         nullptr, accum, NN);
    }
    finalize_kernel<<<1, 1, 0, stream>>>(accum, (float*)d_out);
}

// Round 3
// 1723.093 us; speedup vs baseline: 1.3263x; 1.2514x over previous
//
#include <hip/hip_runtime.h>
#include <hip/hip_bf16.h>

// GCN1: 3-layer GraphConv x 4 graphs -> scalar grand mean.
// R3: atomic-free CSR build. LDS packed-u8 histograms per 12.5k-edge chunk
// (64 chunks/graph), parallel reduce -> degrees/norms + per-chunk prefixes,
// two-level scan -> row starts, LDS-cursor scatter (no global atomics).
// fp8 intermediates for gathers (R2); MFMA bf16 GEMMs; layer-3 GEMM reduces
// relu(y) straight into a double accumulator.

#define NN 50000
#define EN 800000
#define NCH 64            // chunks per graph
#define CHE 12500         // edges per chunk (NCH*CHE == EN)
#define PBS 50016         // padded per-chunk histogram bytes (>= NN, %4==0)
#define SCB 49            // scan blocks per graph (49*1024 >= NN)

typedef unsigned int uint;
typedef unsigned short ushort;
typedef unsigned char uchar;
typedef short s8v __attribute__((ext_vector_type(8)));
typedef float f4v __attribute__((ext_vector_type(4)));
typedef float f2v __attribute__((ext_vector_type(2)));

__device__ inline ushort f2bf(float f) {
    uint u = __float_as_uint(f);
    uint r = (u + 0x7FFFu + ((u >> 16) & 1u)) >> 16;
    return (ushort)r;
}
__device__ inline uint pk2(float lo, float hi) {
    return (uint)f2bf(lo) | ((uint)f2bf(hi) << 16);
}
__device__ inline f4v mfma16(s8v a, s8v b, f4v c) {
    return __builtin_amdgcn_mfma_f32_16x16x32_bf16(a, b, c, 0, 0, 0);
}
__device__ inline uchar f2fp8(float f) {
    return (uchar)(__builtin_amdgcn_cvt_pk_fp8_f32(f, 0.f, 0, false) & 0xFF);
}

struct GP { const int* p[4]; };

// ---- CSR build (atomic-free) ----------------------------------------------

// grid (NCH, 2, 4): chunk b, direction (0=src,1=dst), graph g.
__global__ __launch_bounds__(256) void hist_kernel(GP src, GP dst,
                                                   uint* __restrict__ partS,
                                                   uint* __restrict__ partD) {
    int b = blockIdx.x, dir = blockIdx.y, g = blockIdx.z;
    const int* idx = dir ? dst.p[g] : src.p[g];
    __shared__ uint lh[PBS / 4];
    for (int i = threadIdx.x; i < PBS / 4; i += 256) lh[i] = 0;
    __syncthreads();
    int e0 = b * CHE;
    for (int e = e0 + threadIdx.x; e < e0 + CHE; e += 256) {
        uint n = (uint)idx[e];
        atomicAdd(&lh[n >> 2], 1u << (8 * (n & 3)));   // LDS atomic only
    }
    __syncthreads();
    uint* out = (dir ? partD : partS) + (size_t)(g * NCH + b) * (PBS / 4);
    for (int i = threadIdx.x; i < PBS / 4; i += 256) out[i] = lh[i];
}

// one thread per (g,n): sum partials -> degrees/norms; partD -> excl prefix.
__global__ __launch_bounds__(256) void reduce_kernel(const uchar* __restrict__ partS,
                                                     uchar* __restrict__ partD,
                                                     float* __restrict__ ns,
                                                     float* __restrict__ nd,
                                                     int* __restrict__ degd) {
    int idx = blockIdx.x * 256 + threadIdx.x;
    if (idx >= 4 * NN) return;
    int g = idx / NN, n = idx - g * NN;
    const uchar* ps = partS + (size_t)(g * NCH) * PBS + n;
    uint ss = 0;
    for (int b = 0; b < NCH; b++) ss += ps[(size_t)b * PBS];
    uchar* pd = partD + (size_t)(g * NCH) * PBS + n;
    uint run = 0;
    for (int b = 0; b < NCH; b++) {
        uint v = pd[(size_t)b * PBS];
        pd[(size_t)b * PBS] = (uchar)run;
        run += v;
    }
    ns[idx] = rsqrtf((float)max(ss, 1u));
    nd[idx] = rsqrtf((float)max(run, 1u));
    degd[idx] = (int)run;
}

// two-level exclusive scan of degd -> rs (row starts), per graph.
__global__ __launch_bounds__(1024) void scan1_kernel(const int* __restrict__ degd,
                                                     int* __restrict__ rs_all,
                                                     int* __restrict__ bsum) {
    int j = blockIdx.x, g = blockIdx.y;
    int i = j * 1024 + threadIdx.x;
    int v = (i < NN) ? degd[g * NN + i] : 0;
    int lane = threadIdx.x & 63, w = threadIdx.x >> 6;
    int x = v;
    #pragma unroll
    for (int off = 1; off < 64; off <<= 1) {
        int t = __shfl_up(x, off, 64);
        if (lane >= off) x += t;
    }
    __shared__ int ws[17];
    if (lane == 63) ws[w] = x;
    __syncthreads();
    if (threadIdx.x == 0) {
        int run = 0;
        #pragma unroll
        for (int k = 0; k < 16; k++) { int t = ws[k]; ws[k] = run; run += t; }
        ws[16] = run;
    }
    __syncthreads();
    if (i < NN) rs_all[g * (NN + 1) + i] = ws[w] + x - v;
    if (threadIdx.x == 0) bsum[g * SCB + j] = ws[16];
}

__global__ void scan2_kernel(int* __restrict__ bsum, int* __restrict__ rs_all) {
    int g = threadIdx.x >> 6, lane = threadIdx.x & 63;
    int v = (lane < SCB) ? bsum[g * SCB + lane] : 0;
    int x = v;
    #pragma unroll
    for (int off = 1; off < 64; off <<= 1) {
        int t = __shfl_up(x, off, 64);
        if (lane >= off) x += t;
    }
    if (lane < SCB) bsum[g * SCB + lane] = x - v;   // exclusive
    if (lane == 63) rs_all[g * (NN + 1) + NN] = x;  // total (== EN)
}

__global__ __launch_bounds__(1024) void scan3_kernel(const int* __restrict__ bsum,
                                                     int* __restrict__ rs_all) {
    int j = blockIdx.x, g = blockIdx.y;
    int i = j * 1024 + threadIdx.x;
    int off = bsum[g * SCB + j];
    if (i < NN) rs_all[g * (NN + 1) + i] += off;
}

// grid (NCH, 4): LDS u8 cursors give within-chunk rank; no global atomics.
__global__ __launch_bounds__(256) void scatter_kernel(GP src, GP dst,
                                                      const int* __restrict__ rs_all,
                                                      const uchar* __restrict__ pf,
                                                      int* __restrict__ csr) {
    int b = blockIdx.x, g = blockIdx.y;
    __shared__ uint lc[PBS / 4];
    for (int i = threadIdx.x; i < PBS / 4; i += 256) lc[i] = 0;
    __syncthreads();
    const int* sp = src.p[g];
    const int* dp = dst.p[g];
    const int* rs = rs_all + g * (NN + 1);
    const uchar* pfb = pf + (size_t)(g * NCH + b) * PBS;
    int* csrg = csr + (size_t)g * EN;
    int e0 = b * CHE;
    for (int e = e0 + threadIdx.x; e < e0 + CHE; e += 256) {
        uint d = (uint)dp[e];
        int s = sp[e];
        uint sh = 8 * (d & 3);
        uint old = atomicAdd(&lc[d >> 2], 1u << sh);
        uint r = (old >> sh) & 0xFFu;
        csrg[rs[d] + (int)pfb[d] + (int)r] = s;
    }
}

// ---- weight transpose/pad to bf16: Wt[n][k], stride WS = K+8 ---------------

__global__ __launch_bounds__(256) void wtrans_kernel(const float* __restrict__ W,
                                                     ushort* __restrict__ Wt,
                                                     int Kreal, int WS) {
    int idx = blockIdx.x * 256 + threadIdx.x;
    if (idx >= 320 * WS) return;
    int n = idx / WS, k = idx - n * WS;
    float v = (n < 304 && k < Kreal) ? W[k * 304 + n] : 0.f;
    Wt[idx] = f2bf(v);
}

// ---- prescale: xs = fp8(x * ns), N x 128 (32 dwords/row) -------------------

__global__ __launch_bounds__(256) void prescale_kernel(const float* __restrict__ x,
                                                       const float* __restrict__ ns,
                                                       uint* __restrict__ xs) {
    int idx = blockIdx.x * 256 + threadIdx.x;   // over NN*32 float4s
    if (idx >= NN * 32) return;
    int row = idx >> 5;
    float nv = ns[row];
    float4 v = ((const float4*)x)[idx];
    int p = 0;
    p = __builtin_amdgcn_cvt_pk_fp8_f32(v.x * nv, v.y * nv, p, false);
    p = __builtin_amdgcn_cvt_pk_fp8_f32(v.z * nv, v.w * nv, p, true);
    xs[idx] = (uint)p;
}

// ---- SpMM: one wave per node, CSR gather-accumulate (fp8 in, bf16 out) -----

__global__ __launch_bounds__(256) void spmm128_kernel(const uint* __restrict__ xs,
                                                      const int* __restrict__ rs,
                                                      const int* __restrict__ csr,
                                                      const float* __restrict__ nd,
                                                      uint* __restrict__ out) {
    int wv = threadIdx.x >> 6, lane = threadIdx.x & 63;
    int node = blockIdx.x * 4 + wv;
    int e0 = rs[node], e1 = rs[node + 1];
    int half = lane >> 5, l32 = lane & 31;
    float a0 = 0.f, a1 = 0.f, a2 = 0.f, a3 = 0.f;
    for (int e = e0; e < e1; e += 2) {
        int idx = e + half;
        if (idx < e1) {
            int s = csr[idx];
            uint d = xs[(size_t)s * 32 + l32];
            f2v lo = __builtin_amdgcn_cvt_pk_f32_fp8(d, false);
            f2v hi = __builtin_amdgcn_cvt_pk_f32_fp8(d, true);
            a0 += lo[0]; a1 += lo[1]; a2 += hi[0]; a3 += hi[1];
        }
    }
    a0 += __shfl_xor(a0, 32, 64);
    a1 += __shfl_xor(a1, 32, 64);
    a2 += __shfl_xor(a2, 32, 64);
    a3 += __shfl_xor(a3, 32, 64);
    if (half == 0) {
        float nv = nd[node];
        uint2 o = make_uint2(pk2(a0 * nv, a1 * nv), pk2(a2 * nv, a3 * nv));
        ((uint2*)(out + (size_t)node * 64))[l32] = o;
    }
}

__global__ __launch_bounds__(256) void spmm320_kernel(const uint* __restrict__ h,
                                                      const int* __restrict__ rs,
                                                      const int* __restrict__ csr,
                                                      const float* __restrict__ nd,
                                                      uint* __restrict__ out) {
    int wv = threadIdx.x >> 6, lane = threadIdx.x & 63;
    int node = blockIdx.x * 4 + wv;
    int e0 = rs[node], e1 = rs[node + 1];
    float a0 = 0.f, a1 = 0.f, a2 = 0.f, a3 = 0.f;
    float b0 = 0.f, b1 = 0.f, b2 = 0.f, b3 = 0.f;
    bool tail = lane < 16;
    for (int e = e0; e < e1; e++) {
        int s = __builtin_amdgcn_readfirstlane(csr[e]);
        const uint* row = h + (size_t)s * 80;
        uint d0 = row[lane];
        f2v lo = __builtin_amdgcn_cvt_pk_f32_fp8(d0, false);
        f2v hi = __builtin_amdgcn_cvt_pk_f32_fp8(d0, true);
        a0 += lo[0]; a1 += lo[1]; a2 += hi[0]; a3 += hi[1];
        if (tail) {
            uint d1 = row[64 + lane];
            f2v lo1 = __builtin_amdgcn_cvt_pk_f32_fp8(d1, false);
            f2v hi1 = __builtin_amdgcn_cvt_pk_f32_fp8(d1, true);
            b0 += lo1[0]; b1 += lo1[1]; b2 += hi1[0]; b3 += hi1[1];
        }
    }
    float nv = nd[node];
    uint* orow = out + (size_t)node * 160;
    ((uint2*)orow)[lane] = make_uint2(pk2(a0 * nv, a1 * nv), pk2(a2 * nv, a3 * nv));
    if (tail)
        ((uint2*)orow)[64 + lane] = make_uint2(pk2(b0 * nv, b1 * nv), pk2(b2 * nv, b3 * nv));
}

// ---- GEMM: C[M x 320] = A[M x K] @ Wt^T, epilogue relu(+bias) --------------

template<int KSTEPS, bool REDUCE>
__global__ __launch_bounds__(256) void gemm_kernel(const ushort* __restrict__ A, int astride,
                                                   const ushort* __restrict__ Wt,
                                                   const float* __restrict__ bias,
                                                   const float* __restrict__ ns,
                                                   uchar* __restrict__ Hout,
                                                   double* __restrict__ accum,
                                                   int M) {
    constexpr int K = KSTEPS * 32;
    constexpr int WS = K + 8;   // pad: 2-way LDS conflicts only (free)
    __shared__ __align__(16) ushort wt[80 * WS];
    __shared__ float redbuf[4];
    int tid = threadIdx.x, lane = tid & 63, wv = tid >> 6;
    int nb = blockIdx.y * 80;
    int r0 = blockIdx.x * 128 + wv * 32;

    {   // stage 80 rows of Wt (16B vectors)
        const s8v* src = (const s8v*)(Wt + (size_t)nb * WS);
        s8v* dst = (s8v*)wt;
        for (int i = tid; i < 80 * WS / 8; i += 256) dst[i] = src[i];
    }
    __syncthreads();

    f4v acc[2][5];
    #pragma unroll
    for (int t = 0; t < 2; t++)
        #pragma unroll
        for (int j = 0; j < 5; j++) acc[t][j] = (f4v){0.f, 0.f, 0.f, 0.f};

    int m15 = lane & 15;
    int kq = (lane >> 4) * 8;
    int ar0 = min(r0 + m15, M - 1);
    int ar1 = min(r0 + 16 + m15, M - 1);
    const ushort* a0p = A + (size_t)ar0 * astride + kq;
    const ushort* a1p = A + (size_t)ar1 * astride + kq;
    const ushort* bb = wt + (size_t)m15 * WS + kq;

    #pragma unroll
    for (int ks = 0; ks < KSTEPS; ks++) {
        s8v af0 = *(const s8v*)(a0p + ks * 32);
        s8v af1 = *(const s8v*)(a1p + ks * 32);
        #pragma unroll
        for (int nt = 0; nt < 5; nt++) {
            s8v bf = *(const s8v*)(bb + nt * 16 * WS + ks * 32);
            acc[0][nt] = mfma16(af0, bf, acc[0][nt]);
            acc[1][nt] = mfma16(af1, bf, acc[1][nt]);
        }
    }

    int rq = (lane >> 4) * 4;   // C/D: col = lane&15, row = (lane>>4)*4 + reg
    if constexpr (!REDUCE) {
        float nsv[2][4];
        #pragma unroll
        for (int t = 0; t < 2; t++)
            #pragma unroll
            for (int r = 0; r < 4; r++) {
                int row = r0 + t * 16 + rq + r;
                nsv[t][r] = (row < M) ? ns[row] : 0.f;
            }
        #pragma unroll
        for (int nt = 0; nt < 5; nt++) {
            int col = nb + nt * 16 + m15;
            float bv = (col < 304) ? bias[col] : 0.f;
            #pragma unroll
            for (int t = 0; t < 2; t++)
                #pragma unroll
                for (int r = 0; r < 4; r++) {
                    int row = r0 + t * 16 + rq + r;
                    if (row < M) {
                        float y = fmaxf(acc[t][nt][r] + bv, 0.f) * nsv[t][r];
                        Hout[(size_t)row * 320 + col] = f2fp8(y);
                    }
                }
        }
    } else {
        float s = 0.f;
        #pragma unroll
        for (int nt = 0; nt < 5; nt++) {
            int col = nb + nt * 16 + m15;
            float bv = (col < 304) ? bias[col] : 0.f;
            #pragma unroll
            for (int t = 0; t < 2; t++)
                #pragma unroll
                for (int r = 0; r < 4; r++) {
                    int row = r0 + t * 16 + rq + r;
                    if (row < M && col < 304) s += fmaxf(acc[t][nt][r] + bv, 0.f);
                }
        }
        #pragma unroll
        for (int off = 32; off; off >>= 1) s += __shfl_xor(s, off, 64);
        if (lane == 0) redbuf[wv] = s;
        __syncthreads();
        if (tid == 0) {
            double b = (double)redbuf[0] + redbuf[1] + redbuf[2] + redbuf[3];
            atomicAdd(accum, b);
        }
    }
}

__global__ void finalize_kernel(const double* __restrict__ accum, float* __restrict__ out) {
    out[0] = (float)(accum[0] / (double)(4.0 * NN * 304.0));
}

// ---- host ------------------------------------------------------------------

extern "C" void kernel_launch(void* const* d_in, const int* in_sizes, int n_in,
                              void* d_out, int out_size, void* d_ws, size_t ws_size,
                              hipStream_t stream) {
    char* w = (char*)d_ws;
    auto alloc = [&](size_t bytes) {
        char* p = w;
        w += (bytes + 255) & ~(size_t)255;
        return p;
    };
    double* accum  = (double*)alloc(256);
    int*    degd   = (int*)alloc((size_t)4 * NN * 4);
    int*    rs     = (int*)alloc((size_t)4 * (NN + 1) * 4);
    int*    bsum   = (int*)alloc((size_t)4 * SCB * 4);
    float*  nsrc   = (float*)alloc((size_t)4 * NN * 4);
    float*  ndst   = (float*)alloc((size_t)4 * NN * 4);
    int*    csr    = (int*)alloc((size_t)4 * EN * 4);
    ushort* wt1    = (ushort*)alloc((size_t)320 * 136 * 2);
    ushort* wt2    = (ushort*)alloc((size_t)320 * 328 * 2);
    ushort* wt3    = (ushort*)alloc((size_t)320 * 328 * 2);
    uint*   partS  = (uint*)alloc((size_t)4 * NCH * PBS);      // 12.8 MB
    uint*   partD  = (uint*)alloc((size_t)4 * NCH * PBS);      // 12.8 MB
    uint*   hbuf   = (uint*)alloc((size_t)NN * 80 * 4);        // fp8 N x 320
    uint*   mbuf   = (uint*)alloc((size_t)NN * 160 * 4);       // bf16 N x 320
    // partS/partD are dead after scatter: alias the layer-1 buffers onto them.
    uint*   xs     = partS;   // fp8  N x 128: NN*32*4 = 6.4 MB  <= 12.8 MB
    uint*   m1     = partD;   // bf16 N x 128: NN*64*4 = 12.8 MB <= 12.8 MB

    hipMemsetAsync(accum, 0, 256, stream);

    wtrans_kernel<<<(320 * 136 + 255) / 256, 256, 0, stream>>>((const float*)d_in[12], wt1, 128, 136);
    wtrans_kernel<<<(320 * 328 + 255) / 256, 256, 0, stream>>>((const float*)d_in[14], wt2, 304, 328);
    wtrans_kernel<<<(320 * 328 + 255) / 256, 256, 0, stream>>>((const float*)d_in[16], wt3, 304, 328);

    GP S, D;
    for (int g = 0; g < 4; g++) {
        S.p[g] = (const int*)d_in[1 + 3 * g];
        D.p[g] = (const int*)d_in[2 + 3 * g];
    }
    hist_kernel<<<dim3(NCH, 2, 4), 256, 0, stream>>>(S, D, partS, partD);
    reduce_kernel<<<(4 * NN + 255) / 256, 256, 0, stream>>>((const uchar*)partS, (uchar*)partD,
                                                            nsrc, ndst, degd);
    scan1_kernel<<<dim3(SCB, 4), 1024, 0, stream>>>(degd, rs, bsum);
    scan2_kernel<<<1, 256, 0, stream>>>(bsum, rs);
    scan3_kernel<<<dim3(SCB, 4), 1024, 0, stream>>>(bsum, rs);
    scatter_kernel<<<dim3(NCH, 4), 256, 0, stream>>>(S, D, rs, (const uchar*)partD, csr);

    const float* b1 = (const float*)d_in[13];
    const float* b2 = (const float*)d_in[15];
    const float* b3 = (const float*)d_in[17];
    dim3 ggrid((NN + 127) / 128, 4);

    for (int g = 0; g < 4; g++) {
        const float* xin = (const float*)d_in[3 * g];
        const float* nsg = nsrc + g * NN;
        const float* ndg = ndst + g * NN;
        const int* rsg = rs + g * (NN + 1);
        const int* csrg = csr + (size_t)g * EN;

        prescale_kernel<<<(NN * 32 + 255) / 256, 256, 0, stream>>>(xin, nsg, xs);
        spmm128_kernel<<<NN / 4, 256, 0, stream>>>(xs, rsg, csrg, ndg, m1);
        gemm_kernel<4, false><<<ggrid, 256, 0, stream>>>((const ushort*)m1, 128, wt1, b1, nsg,
                                                         (uchar*)hbuf, nullptr, NN);
        spmm320_kernel<<<NN / 4, 256, 0, stream>>>(hbuf, rsg, csrg, ndg, mbuf);
        gemm_kernel<10, false><<<ggrid, 256, 0, stream>>>((const ushort*)mbuf, 320, wt2, b2, nsg,
                                                          (uchar*)hbuf, nullptr, NN);
        spmm320_kernel<<<NN / 4, 256, 0, stream>>>(hbuf, rsg, csrg, ndg, mbuf);
        gemm_kernel<10, true><<<ggrid, 256, 0, stream>>>((const ushort*)mbuf, 320, wt3, b3, nullptr,
                                                         nullptr, accum, NN);
    }
    finalize_kernel<<<1, 1, 0, stream>>>(accum, (float*)d_out);
}